// Round 4
// baseline (109.988 us; speedup 1.0000x reference)
//
#include <hip/hip_runtime.h>
#include <hip/hip_bf16.h>
#include <cstdint>

// adknnLoss: N=8192, M=128.
//   A = L*X; B = (X@Wnet + bnet)*X
//   dist[i,j] = ||A_i - B_j||; drum = exp(-dist)
//   pred = (drum@Y)/drum.sum(1); loss = sum((Y-pred)^2)
//
// Round 7: prep rewritten on MFMA (was VALU+LDS-bound, ~7us of ~18us kernel
// budget). Computes (X@W)^T = W^T @ X^T per 16-sample tile, one wave/tile,
// NO LDS, no barriers:
//   B-operand = X^T fragments (contiguous float8 per lane, same addresses
//     reused for the A-side L*X elementwise + Asw store)
//   A-operand = W^T fragments (8 strided scalar loads, L2/L1-hot)
//   C-init    = bnet[c] (folded add)
//   D layout: lane holds 4 consecutive features of sample j=lane&15 ->
//     one aligned uint2 store per tile into the Bsw swizzle.
// Norms via shfl_xor(16)+shfl_xor(32). Pairwise/finish unchanged from R6:
//   s = a~.b~ + Cinit(-half-norms) = -K2*d2,  w = exp2(-sqrt(abs(s))).

#define N_ 8192
#define M_ 128
#define SQRT2K2_ 2.0402789f  // sqrt(2*(log2 e)^2); dot of scaled ops = 2*K2*(a.b)

typedef __bf16 bf16x8 __attribute__((ext_vector_type(8)));
typedef float  f32x4  __attribute__((ext_vector_type(4)));
typedef unsigned int u32;

__device__ __forceinline__ unsigned short f2bf(float f) {
    unsigned int x = __float_as_uint(f);
    unsigned int r = x + 0x7fffu + ((x >> 16) & 1u);
    return (unsigned short)(r >> 16);
}

// Swizzled fragment layout (A and B operands of mfma_f32_16x16x32_bf16):
//   elem_off(row,k) = (row>>4)*2048 + (k>>5)*512 + ((k>>3)&3)*128 + (row&15)*8 + (k&7)
// Wave fragment load for (group g, ks): base + g*2048 + ks*512 + lane*8
// -> lane-contiguous 16 B/lane global_load_dwordx4.

// ---------------------------------------------------------------------------
// prep: 128 blocks x 256 thr (4 waves), one 16-sample tile per wave, no LDS.
//   Asw = swz(bf16(L*X*s)); Bsw = swz(bf16((X@Wnet+bnet)*X*s)), s=sqrt(2K2)
//   naS = -0.5*||a~||^2; nbY = (-0.5*||b~||^2, Y); zero sumw/sumwy/out.
// ---------------------------------------------------------------------------
__global__ __launch_bounds__(256) void prep_kernel(
    const float* __restrict__ L, const float* __restrict__ X,
    const float* __restrict__ Y, const float* __restrict__ Wnet,
    const float* __restrict__ bnet,
    unsigned short* __restrict__ Asw, unsigned short* __restrict__ Bsw,
    float* __restrict__ naS, float2* __restrict__ nbY,
    float* __restrict__ sumw, float* __restrict__ sumwy,
    float* __restrict__ out)
{
    const int tid  = threadIdx.x;
    const int wv   = tid >> 6;
    const int lane = tid & 63;
    const int ln16 = lane & 15;
    const int quad = lane >> 4;
    const int g    = blockIdx.x * 4 + wv;   // 16-sample tile index
    const int j    = g * 16 + ln16;         // this lane's sample

    // ---- X fragments (GEMM B-operand) + A-side (L*X) elementwise ----
    bf16x8 xfrag[4];
    float na_part = 0.f;
    #pragma unroll
    for (int ks = 0; ks < 4; ++ks) {
        const int k0 = quad * 8 + ks * 32;
        const float4 xlo = *(const float4*)(X + (size_t)j * 128 + k0);
        const float4 xhi = *(const float4*)(X + (size_t)j * 128 + k0 + 4);
        const float4 llo = *(const float4*)(L + (size_t)j * 128 + k0);
        const float4 lhi = *(const float4*)(L + (size_t)j * 128 + k0 + 4);
        const float xe[8] = {xlo.x, xlo.y, xlo.z, xlo.w, xhi.x, xhi.y, xhi.z, xhi.w};
        const float le[8] = {llo.x, llo.y, llo.z, llo.w, lhi.x, lhi.y, lhi.z, lhi.w};
        unsigned short xp[8], ap[8];
        #pragma unroll
        for (int e = 0; e < 8; ++e) {
            xp[e] = f2bf(xe[e]);
            float a = le[e] * xe[e] * SQRT2K2_;
            unsigned short ua = f2bf(a);
            ap[e] = ua;
            float af = __uint_as_float((u32)ua << 16);
            na_part = fmaf(af, af, na_part);
        }
        uint4 xi = make_uint4(xp[0] | ((u32)xp[1] << 16), xp[2] | ((u32)xp[3] << 16),
                              xp[4] | ((u32)xp[5] << 16), xp[6] | ((u32)xp[7] << 16));
        xfrag[ks] = *(bf16x8*)&xi;
        uint4 ai = make_uint4(ap[0] | ((u32)ap[1] << 16), ap[2] | ((u32)ap[3] << 16),
                              ap[4] | ((u32)ap[5] << 16), ap[6] | ((u32)ap[7] << 16));
        *(uint4*)(Asw + (size_t)g * 2048 + (size_t)ks * 512 + (size_t)lane * 8) = ai;
    }
    na_part += __shfl_xor(na_part, 16, 64);
    na_part += __shfl_xor(na_part, 32, 64);
    if (lane < 16) naS[j] = -0.5f * na_part;

    // ---- GEMM: D = W^T @ X^T (+bnet), tile by 16 output features ----
    float nb_part = 0.f;
    #pragma unroll
    for (int ct = 0; ct < 8; ++ct) {
        const int cb = ct * 16 + quad * 4;       // this lane's 4 feature rows of D
        const int c  = ct * 16 + ln16;           // A-operand row for this lane
        const float4 bn = *(const float4*)(bnet + cb);
        f32x4 s;
        s[0] = bn.x; s[1] = bn.y; s[2] = bn.z; s[3] = bn.w;
        #pragma unroll
        for (int ks = 0; ks < 4; ++ks) {
            unsigned short wp[8];
            #pragma unroll
            for (int e = 0; e < 8; ++e) {
                const int k = quad * 8 + e + ks * 32;
                wp[e] = f2bf(Wnet[(size_t)k * 128 + c]);
            }
            uint4 wi = make_uint4(wp[0] | ((u32)wp[1] << 16), wp[2] | ((u32)wp[3] << 16),
                                  wp[4] | ((u32)wp[5] << 16), wp[6] | ((u32)wp[7] << 16));
            bf16x8 wfrag = *(bf16x8*)&wi;
            s = __builtin_amdgcn_mfma_f32_16x16x32_bf16(wfrag, xfrag[ks], s, 0, 0, 0);
        }
        // s[r] = (X@W)[j][cb+r] + bnet[cb+r]
        const float4 xv = *(const float4*)(X + (size_t)j * 128 + cb);
        const float xe2[4] = {xv.x, xv.y, xv.z, xv.w};
        unsigned short bp[4];
        #pragma unroll
        for (int r = 0; r < 4; ++r) {
            float b = s[r] * xe2[r] * SQRT2K2_;
            unsigned short ub = f2bf(b);
            bp[r] = ub;
            float bf_ = __uint_as_float((u32)ub << 16);
            nb_part = fmaf(bf_, bf_, nb_part);
        }
        size_t off = (size_t)g * 2048 + (size_t)(cb >> 5) * 512
                   + (size_t)((cb >> 3) & 3) * 128 + (size_t)ln16 * 8 + (cb & 7);
        *(uint2*)(Bsw + off) = make_uint2(bp[0] | ((u32)bp[1] << 16),
                                          bp[2] | ((u32)bp[3] << 16));
    }
    nb_part += __shfl_xor(nb_part, 16, 64);
    nb_part += __shfl_xor(nb_part, 32, 64);
    if (lane < 16) nbY[j] = make_float2(-0.5f * nb_part, Y[j]);

    // ---- zero accumulators ----
    const int z0 = blockIdx.x * 64;
    if (tid < 64) sumw[z0 + tid] = 0.f;
    else if (tid < 128) sumwy[z0 + tid - 64] = 0.f;
    if (blockIdx.x == 0 && tid == 128) out[0] = 0.f;
}

// ---------------------------------------------------------------------------
// pairwise: grid (32, 16), 256 thr (4 waves). i-tile 256 rows (64/wave = rt 0..3),
// j-chunk 512 cols = 32 groups of 16. NO LDS, no barriers: B fragments are
// lane-contiguous global_load_dwordx4 from the L2-resident swizzled Bsw;
// waves run fully independently. Norm terms pre-folded into MFMA C-init.
// ---------------------------------------------------------------------------
__global__ __launch_bounds__(256, 2) void pairwise_kernel(
    const unsigned short* __restrict__ Asw, const unsigned short* __restrict__ Bsw,
    const float* __restrict__ naS, const float2* __restrict__ nbY,
    float* __restrict__ sumw, float* __restrict__ sumwy)
{
    const int tid  = threadIdx.x;
    const int wv   = tid >> 6;
    const int lane = tid & 63;
    const int ln16 = lane & 15;
    const int quad = lane >> 4;
    const int i0   = blockIdx.x * 256;
    const int j0   = blockIdx.y * 512;

    // persistent A fragments + negated half-norms (64 rows per wave)
    bf16x8 afrag[4][4];
    float  nna[4][4];
    #pragma unroll
    for (int rt = 0; rt < 4; ++rt) {
        const int gA = (i0 >> 4) + wv * 4 + rt;
        const unsigned short* ap = Asw + (size_t)gA * 2048 + lane * 8;
        #pragma unroll
        for (int ks = 0; ks < 4; ++ks)
            afrag[rt][ks] = *(const bf16x8*)(ap + ks * 512);
        #pragma unroll
        for (int r = 0; r < 4; ++r)
            nna[rt][r] = naS[gA * 16 + quad * 4 + r];
    }

    float accw[4][4], accwy[4][4];
    #pragma unroll
    for (int rt = 0; rt < 4; ++rt)
        #pragma unroll
        for (int r = 0; r < 4; ++r) { accw[rt][r] = 0.f; accwy[rt][r] = 0.f; }

    const unsigned short* bbase = Bsw + (size_t)(j0 >> 4) * 2048 + lane * 8;
    const float2* nbbase = nbY + j0 + ln16;

    #pragma unroll 2
    for (int ct = 0; ct < 32; ++ct) {
        const unsigned short* bp = bbase + (size_t)ct * 2048;
        bf16x8 bfrag[4];
        #pragma unroll
        for (int ks = 0; ks < 4; ++ks)
            bfrag[ks] = *(const bf16x8*)(bp + ks * 512);
        const float2 nv = nbbase[ct * 16];

        #pragma unroll
        for (int rt = 0; rt < 4; ++rt) {
            f32x4 s;
            #pragma unroll
            for (int r = 0; r < 4; ++r) s[r] = nna[rt][r] + nv.x;
            #pragma unroll
            for (int ks = 0; ks < 4; ++ks)
                s = __builtin_amdgcn_mfma_f32_16x16x32_bf16(
                        afrag[rt][ks], bfrag[ks], s, 0, 0, 0);
            // s = a~.b~ - 0.5||a~||^2 - 0.5||b~||^2 = -K2*d2
            #pragma unroll
            for (int r = 0; r < 4; ++r) {
                float w = __builtin_amdgcn_exp2f(
                              -__builtin_amdgcn_sqrtf(__builtin_fabsf(s[r])));
                accw[rt][r] += w;
                accwy[rt][r] = fmaf(w, nv.y, accwy[rt][r]);
            }
        }
    }

    // reduce over the 16 column-lanes, one atomic per row
    #pragma unroll
    for (int rt = 0; rt < 4; ++rt)
        #pragma unroll
        for (int r = 0; r < 4; ++r) {
            float w  = accw[rt][r];
            float wy = accwy[rt][r];
            #pragma unroll
            for (int m = 1; m <= 8; m <<= 1) {
                w  += __shfl_xor(w,  m, 64);
                wy += __shfl_xor(wy, m, 64);
            }
            if (ln16 == 0) {
                int row = i0 + wv * 64 + rt * 16 + quad * 4 + r;
                atomicAdd(&sumw[row],  w);
                atomicAdd(&sumwy[row], wy);
            }
        }
}

// ---------------------------------------------------------------------------
// finish: 8 blocks x 256 thr; each thread handles 4 rows (float4).
// Partial loss per block -> atomicAdd into out (zeroed by prep).
// ---------------------------------------------------------------------------
__global__ __launch_bounds__(256) void finish_kernel(
    const float* __restrict__ Y, const float* __restrict__ sumw,
    const float* __restrict__ sumwy, float* __restrict__ out)
{
    __shared__ float red[4];
    const int tid = threadIdx.x;
    const int idx = blockIdx.x * 256 + tid;
    float4 w4  = ((const float4*)sumw)[idx];
    float4 wy4 = ((const float4*)sumwy)[idx];
    float4 y4  = ((const float4*)Y)[idx];
    const float we[4]  = {w4.x, w4.y, w4.z, w4.w};
    const float wye[4] = {wy4.x, wy4.y, wy4.z, wy4.w};
    const float ye[4]  = {y4.x, y4.y, y4.z, y4.w};
    float acc = 0.f;
    #pragma unroll
    for (int e = 0; e < 4; ++e) {
        float pred = wye[e] * __builtin_amdgcn_rcpf(we[e]);
        float d = ye[e] - pred;
        acc = fmaf(d, d, acc);
    }
    #pragma unroll
    for (int m = 1; m < 64; m <<= 1) acc += __shfl_xor(acc, m, 64);
    if ((tid & 63) == 0) red[tid >> 6] = acc;
    __syncthreads();
    if (tid == 0) {
        float v = red[0] + red[1] + red[2] + red[3];
        atomicAdd(out, v);
    }
}

// ---------------------------------------------------------------------------
extern "C" void kernel_launch(void* const* d_in, const int* in_sizes, int n_in,
                              void* d_out, int out_size, void* d_ws, size_t ws_size,
                              hipStream_t stream)
{
    const float* L    = (const float*)d_in[0];
    const float* X    = (const float*)d_in[1];
    const float* Y    = (const float*)d_in[2];
    const float* Wnet = (const float*)d_in[3];
    const float* bnet = (const float*)d_in[4];
    float* out = (float*)d_out;

    // ws: Asw 2MB | Bsw 2MB | naS 32KB | nbY 64KB | sumw 32KB | sumwy 32KB
    char* ws = (char*)d_ws;
    unsigned short* Asw = (unsigned short*)(ws);
    unsigned short* Bsw = (unsigned short*)(ws + (size_t)2 * 1024 * 1024);
    float*  naS   = (float*) (ws + (size_t)4 * 1024 * 1024);
    float2* nbYp  = (float2*)(ws + (size_t)4 * 1024 * 1024 + 32 * 1024);
    float*  sumw  = (float*) (ws + (size_t)4 * 1024 * 1024 + 96 * 1024);
    float*  sumwy = (float*) (ws + (size_t)4 * 1024 * 1024 + 128 * 1024);

    prep_kernel<<<N_ / 64, 256, 0, stream>>>(L, X, Y, Wnet, bnet,
                                             Asw, Bsw, naS, nbYp, sumw, sumwy, out);
    pairwise_kernel<<<dim3(N_ / 256, 16), 256, 0, stream>>>(Asw, Bsw, naS, nbYp,
                                                            sumw, sumwy);
    finish_kernel<<<8, 256, 0, stream>>>(Y, sumw, sumwy, out);
}

// Round 5
// 104.392 us; speedup vs baseline: 1.0536x; 1.0536x over previous
//
#include <hip/hip_runtime.h>
#include <hip/hip_bf16.h>
#include <cstdint>

// adknnLoss: N=8192, M=128.
//   A = L*X; B = (X@Wnet + bnet)*X
//   dist[i,j] = ||A_i - B_j||; drum = exp(-dist)
//   pred = (drum@Y)/drum.sum(1); loss = sum((Y-pred)^2)
//
// Round 8: revert to R6/R3 verified structure (R7's MFMA prep regressed:
// scalar strided W-gathers + 128-block grid). Prep kept on VALU but its
// LDS-instruction-issue bottleneck halved twice:
//   - 4 rows/thread (32 rows/block, 256 blocks): 4 W ds_read_b128 feed
//     64 FMAs (was 32) -> W-side LDS instrs halved
//   - X read straight from global (uniform per 32-lane group -> one L1-hot
//     16B broadcast segment, VMEM pipe) -> no Xs tile, LDS instrs 6->4/iter
// Pairwise/finish unchanged: s = a~.b~ + Cinit(-half-norms) = -K2*d2,
//   w = exp2(-sqrt(abs(s))).

#define N_ 8192
#define M_ 128
#define SQRT2K2_ 2.0402789f  // sqrt(2*(log2 e)^2); dot of scaled ops = 2*K2*(a.b)

typedef __bf16 bf16x8 __attribute__((ext_vector_type(8)));
typedef float  f32x4  __attribute__((ext_vector_type(4)));
typedef unsigned int u32;

__device__ __forceinline__ unsigned short f2bf(float f) {
    unsigned int x = __float_as_uint(f);
    unsigned int r = x + 0x7fffu + ((x >> 16) & 1u);
    return (unsigned short)(r >> 16);
}

// Swizzled fragment layout (A and B operands of mfma_f32_16x16x32_bf16):
//   elem_off(row,k) = (row>>4)*2048 + (k>>5)*512 + ((k>>3)&3)*128 + (row&15)*8 + (k&7)
// Wave fragment load for (group g, ks): base + g*2048 + ks*512 + lane*8
// -> lane-contiguous 16 B/lane global_load_dwordx4.

// ---------------------------------------------------------------------------
// prep: 256 blocks x 256 thr; 32 rows/block, 4 rows/thread. Wnet in LDS
// (64 KB, only LDS use). thread = (rr,k4): rows rr*4..rr*4+3, cols 4*k4..+3.
//   Asw = swz(bf16(L*X*s)); Bsw = swz(bf16((X@Wnet+bnet)*X*s)), s=sqrt(2K2)
//   naS = -0.5*||a~||^2; nbY = (-0.5*||b~||^2, Y); zero sumw/sumwy/out.
// ---------------------------------------------------------------------------
__global__ __launch_bounds__(256) void prep_kernel(
    const float* __restrict__ L, const float* __restrict__ X,
    const float* __restrict__ Y, const float* __restrict__ Wnet,
    const float* __restrict__ bnet,
    unsigned short* __restrict__ Asw, unsigned short* __restrict__ Bsw,
    float* __restrict__ naS, float2* __restrict__ nbY,
    float* __restrict__ sumw, float* __restrict__ sumwy,
    float* __restrict__ out)
{
    __shared__ float Ws[128 * 128];  // 64 KB
    const int tid  = threadIdx.x;
    const int row0 = blockIdx.x * 32;
    const int k4   = tid & 31;
    const int rr   = tid >> 5;

    #pragma unroll
    for (int i = 0; i < 16; ++i)
        ((float4*)Ws)[tid + i * 256] = ((const float4*)Wnet)[tid + i * 256];
    __syncthreads();

    const float* xrow[4];
    #pragma unroll
    for (int j = 0; j < 4; ++j)
        xrow[j] = X + (size_t)(row0 + rr * 4 + j) * 128;

    float acc[4][4];
    #pragma unroll
    for (int j = 0; j < 4; ++j)
        #pragma unroll
        for (int e = 0; e < 4; ++e) acc[j][e] = 0.f;

    #pragma unroll 2
    for (int c4 = 0; c4 < 128; c4 += 4) {
        const float4 wc0 = *(const float4*)&Ws[(c4 + 0) * 128 + k4 * 4];
        const float4 wc1 = *(const float4*)&Ws[(c4 + 1) * 128 + k4 * 4];
        const float4 wc2 = *(const float4*)&Ws[(c4 + 2) * 128 + k4 * 4];
        const float4 wc3 = *(const float4*)&Ws[(c4 + 3) * 128 + k4 * 4];
        const float4 wce[4] = {wc0, wc1, wc2, wc3};
        #pragma unroll
        for (int j = 0; j < 4; ++j) {
            const float4 xv = *(const float4*)(xrow[j] + c4);
            const float xe[4] = {xv.x, xv.y, xv.z, xv.w};
            #pragma unroll
            for (int c = 0; c < 4; ++c) {
                acc[j][0] = fmaf(xe[c], wce[c].x, acc[j][0]);
                acc[j][1] = fmaf(xe[c], wce[c].y, acc[j][1]);
                acc[j][2] = fmaf(xe[c], wce[c].z, acc[j][2]);
                acc[j][3] = fmaf(xe[c], wce[c].w, acc[j][3]);
            }
        }
    }

    const float4 bn4 = *(const float4*)(bnet + k4 * 4);
    float napart[4], nbpart[4];
    #pragma unroll
    for (int j = 0; j < 4; ++j) {
        const int ln32 = rr * 4 + j;
        const int row  = row0 + ln32;
        const float4 xv = *(const float4*)(xrow[j] + k4 * 4);
        const float4 l4 = *(const float4*)(L + (size_t)row * 128 + k4 * 4);
        unsigned short apk[4], bpk[4];
        float nA_ = 0.f, nB_ = 0.f;
        const float xe[4] = {xv.x, xv.y, xv.z, xv.w};
        const float le[4] = {l4.x, l4.y, l4.z, l4.w};
        const float be[4] = {bn4.x, bn4.y, bn4.z, bn4.w};
        #pragma unroll
        for (int e = 0; e < 4; ++e) {
            float a = le[e] * xe[e] * SQRT2K2_;
            float b = (acc[j][e] + be[e]) * xe[e] * SQRT2K2_;
            unsigned short ua = f2bf(a), ub = f2bf(b);
            apk[e] = ua; bpk[e] = ub;
            float af = __uint_as_float((u32)ua << 16);
            float bf = __uint_as_float((u32)ub << 16);
            nA_ = fmaf(af, af, nA_);
            nB_ = fmaf(bf, bf, nB_);
        }
        napart[j] = nA_; nbpart[j] = nB_;
        const int g  = blockIdx.x * 2 + (ln32 >> 4);
        const int ln = ln32 & 15;
        size_t off = (size_t)g * 2048 + (size_t)(k4 >> 3) * 512
                   + (size_t)((k4 >> 1) & 3) * 128 + (size_t)ln * 8 + (k4 & 1) * 4;
        *(uint2*)(Asw + off) = make_uint2((u32)apk[0] | ((u32)apk[1] << 16),
                                          (u32)apk[2] | ((u32)apk[3] << 16));
        *(uint2*)(Bsw + off) = make_uint2((u32)bpk[0] | ((u32)bpk[1] << 16),
                                          (u32)bpk[2] | ((u32)bpk[3] << 16));
    }

    #pragma unroll
    for (int m = 1; m <= 16; m <<= 1) {
        #pragma unroll
        for (int j = 0; j < 4; ++j) {
            napart[j] += __shfl_xor(napart[j], m, 64);
            nbpart[j] += __shfl_xor(nbpart[j], m, 64);
        }
    }
    if (k4 == 0) {
        #pragma unroll
        for (int j = 0; j < 4; ++j) {
            int row = row0 + rr * 4 + j;
            naS[row] = -0.5f * napart[j];
            nbY[row] = make_float2(-0.5f * nbpart[j], Y[row]);
        }
    }
    if (tid < 32) sumw[row0 + tid] = 0.f;
    else if (tid < 64) sumwy[row0 + tid - 32] = 0.f;
    if (blockIdx.x == 0 && tid == 64) out[0] = 0.f;
}

// ---------------------------------------------------------------------------
// pairwise: grid (32, 16), 256 thr (4 waves). i-tile 256 rows (64/wave = rt 0..3),
// j-chunk 512 cols = 32 groups of 16. NO LDS, no barriers: B fragments are
// lane-contiguous global_load_dwordx4 from the L2-resident swizzled Bsw;
// waves run fully independently. Norm terms pre-folded into MFMA C-init.
// ---------------------------------------------------------------------------
__global__ __launch_bounds__(256, 2) void pairwise_kernel(
    const unsigned short* __restrict__ Asw, const unsigned short* __restrict__ Bsw,
    const float* __restrict__ naS, const float2* __restrict__ nbY,
    float* __restrict__ sumw, float* __restrict__ sumwy)
{
    const int tid  = threadIdx.x;
    const int wv   = tid >> 6;
    const int lane = tid & 63;
    const int ln16 = lane & 15;
    const int quad = lane >> 4;
    const int i0   = blockIdx.x * 256;
    const int j0   = blockIdx.y * 512;

    // persistent A fragments + negated half-norms (64 rows per wave)
    bf16x8 afrag[4][4];
    float  nna[4][4];
    #pragma unroll
    for (int rt = 0; rt < 4; ++rt) {
        const int gA = (i0 >> 4) + wv * 4 + rt;
        const unsigned short* ap = Asw + (size_t)gA * 2048 + lane * 8;
        #pragma unroll
        for (int ks = 0; ks < 4; ++ks)
            afrag[rt][ks] = *(const bf16x8*)(ap + ks * 512);
        #pragma unroll
        for (int r = 0; r < 4; ++r)
            nna[rt][r] = naS[gA * 16 + quad * 4 + r];
    }

    float accw[4][4], accwy[4][4];
    #pragma unroll
    for (int rt = 0; rt < 4; ++rt)
        #pragma unroll
        for (int r = 0; r < 4; ++r) { accw[rt][r] = 0.f; accwy[rt][r] = 0.f; }

    const unsigned short* bbase = Bsw + (size_t)(j0 >> 4) * 2048 + lane * 8;
    const float2* nbbase = nbY + j0 + ln16;

    #pragma unroll 2
    for (int ct = 0; ct < 32; ++ct) {
        const unsigned short* bp = bbase + (size_t)ct * 2048;
        bf16x8 bfrag[4];
        #pragma unroll
        for (int ks = 0; ks < 4; ++ks)
            bfrag[ks] = *(const bf16x8*)(bp + ks * 512);
        const float2 nv = nbbase[ct * 16];

        #pragma unroll
        for (int rt = 0; rt < 4; ++rt) {
            f32x4 s;
            #pragma unroll
            for (int r = 0; r < 4; ++r) s[r] = nna[rt][r] + nv.x;
            #pragma unroll
            for (int ks = 0; ks < 4; ++ks)
                s = __builtin_amdgcn_mfma_f32_16x16x32_bf16(
                        afrag[rt][ks], bfrag[ks], s, 0, 0, 0);
            // s = a~.b~ - 0.5||a~||^2 - 0.5||b~||^2 = -K2*d2
            #pragma unroll
            for (int r = 0; r < 4; ++r) {
                float w = __builtin_amdgcn_exp2f(
                              -__builtin_amdgcn_sqrtf(__builtin_fabsf(s[r])));
                accw[rt][r] += w;
                accwy[rt][r] = fmaf(w, nv.y, accwy[rt][r]);
            }
        }
    }

    // reduce over the 16 column-lanes, one atomic per row
    #pragma unroll
    for (int rt = 0; rt < 4; ++rt)
        #pragma unroll
        for (int r = 0; r < 4; ++r) {
            float w  = accw[rt][r];
            float wy = accwy[rt][r];
            #pragma unroll
            for (int m = 1; m <= 8; m <<= 1) {
                w  += __shfl_xor(w,  m, 64);
                wy += __shfl_xor(wy, m, 64);
            }
            if (ln16 == 0) {
                int row = i0 + wv * 64 + rt * 16 + quad * 4 + r;
                atomicAdd(&sumw[row],  w);
                atomicAdd(&sumwy[row], wy);
            }
        }
}

// ---------------------------------------------------------------------------
// finish: 8 blocks x 256 thr; each thread handles 4 rows (float4).
// Partial loss per block -> atomicAdd into out (zeroed by prep).
// ---------------------------------------------------------------------------
__global__ __launch_bounds__(256) void finish_kernel(
    const float* __restrict__ Y, const float* __restrict__ sumw,
    const float* __restrict__ sumwy, float* __restrict__ out)
{
    __shared__ float red[4];
    const int tid = threadIdx.x;
    const int idx = blockIdx.x * 256 + tid;
    float4 w4  = ((const float4*)sumw)[idx];
    float4 wy4 = ((const float4*)sumwy)[idx];
    float4 y4  = ((const float4*)Y)[idx];
    const float we[4]  = {w4.x, w4.y, w4.z, w4.w};
    const float wye[4] = {wy4.x, wy4.y, wy4.z, wy4.w};
    const float ye[4]  = {y4.x, y4.y, y4.z, y4.w};
    float acc = 0.f;
    #pragma unroll
    for (int e = 0; e < 4; ++e) {
        float pred = wye[e] * __builtin_amdgcn_rcpf(we[e]);
        float d = ye[e] - pred;
        acc = fmaf(d, d, acc);
    }
    #pragma unroll
    for (int m = 1; m < 64; m <<= 1) acc += __shfl_xor(acc, m, 64);
    if ((tid & 63) == 0) red[tid >> 6] = acc;
    __syncthreads();
    if (tid == 0) {
        float v = red[0] + red[1] + red[2] + red[3];
        atomicAdd(out, v);
    }
}

// ---------------------------------------------------------------------------
extern "C" void kernel_launch(void* const* d_in, const int* in_sizes, int n_in,
                              void* d_out, int out_size, void* d_ws, size_t ws_size,
                              hipStream_t stream)
{
    const float* L    = (const float*)d_in[0];
    const float* X    = (const float*)d_in[1];
    const float* Y    = (const float*)d_in[2];
    const float* Wnet = (const float*)d_in[3];
    const float* bnet = (const float*)d_in[4];
    float* out = (float*)d_out;

    // ws: Asw 2MB | Bsw 2MB | naS 32KB | nbY 64KB | sumw 32KB | sumwy 32KB
    char* ws = (char*)d_ws;
    unsigned short* Asw = (unsigned short*)(ws);
    unsigned short* Bsw = (unsigned short*)(ws + (size_t)2 * 1024 * 1024);
    float*  naS   = (float*) (ws + (size_t)4 * 1024 * 1024);
    float2* nbYp  = (float2*)(ws + (size_t)4 * 1024 * 1024 + 32 * 1024);
    float*  sumw  = (float*) (ws + (size_t)4 * 1024 * 1024 + 96 * 1024);
    float*  sumwy = (float*) (ws + (size_t)4 * 1024 * 1024 + 128 * 1024);

    prep_kernel<<<N_ / 32, 256, 0, stream>>>(L, X, Y, Wnet, bnet,
                                             Asw, Bsw, naS, nbYp, sumw, sumwy, out);
    pairwise_kernel<<<dim3(N_ / 256, 16), 256, 0, stream>>>(Asw, Bsw, naS, nbYp,
                                                            sumw, sumwy);
    finish_kernel<<<8, 256, 0, stream>>>(Y, sumw, sumwy, out);
}